// Round 1
// baseline (489.292 us; speedup 1.0000x reference)
//
#include <hip/hip_runtime.h>
#include <hip/hip_bf16.h>

// ---------------------------------------------------------------------------
// Fused add + QKV + cross-head attention + output projection, bf16 MFMA.
//
// reference: x=(x_c+x_t) NHWC; q/k/v = x@W.T+b with head-INNER split
// (q[h,c]=q_lin[c*8+h]); 8x8 attention ACROSS heads per token over hd=32;
// concat head-OUTER; out = o@Wo.T+bo -> NCHW.
// The inner/outer permutation is folded into permuted weight rows (prep).
// ---------------------------------------------------------------------------

typedef unsigned short u16;
typedef __bf16 bf16x8 __attribute__((ext_vector_type(8)));
typedef float f32x4 __attribute__((ext_vector_type(4)));
typedef unsigned short u16x8 __attribute__((ext_vector_type(8)));
typedef unsigned short u16x4 __attribute__((ext_vector_type(4)));

constexpr int CH = 256;        // channels
constexpr int HWN = 16384;     // H*W
constexpr int LDX = 264;       // XT row stride (elems): 528B = 16*33 -> 16B-aligned rows, quad stride 4 mod 32
constexpr int LQ = 776;        // QKVT row stride: 1552B, 8B-aligned rows, quad stride 4 mod 32

// ws byte layout
constexpr size_t WS_WQKV = 0;             // 768*256 u16 = 393216
constexpr size_t WS_WO = 393216;          // 256*256 u16 = 131072
constexpr size_t WS_BIAS = 524288;        // 768 f32 = 3072
constexpr size_t WS_O = 528384;           // 131072*256 u16 = 67108864

__device__ __forceinline__ u16 f2bf(float f) {
    unsigned u = __builtin_bit_cast(unsigned, f);
    unsigned r = u + 0x7FFFu + ((u >> 16) & 1u);   // RNE
    return (u16)(r >> 16);
}
__device__ __forceinline__ float bf2f(u16 u) {
    return __builtin_bit_cast(float, (unsigned)u << 16);
}

// --- prep: permuted bf16 weights + permuted biases -------------------------
// row j of Wq' = row (j%32)*8 + j/32 of Wq  (head-inner -> head-outer fold)
__global__ void prep_kernel(const float* __restrict__ Wq, const float* __restrict__ Wk,
                            const float* __restrict__ Wv, const float* __restrict__ Wo,
                            const float* __restrict__ bq, const float* __restrict__ bk,
                            const float* __restrict__ bv,
                            u16* __restrict__ Wqkv_b, u16* __restrict__ Wo_b,
                            float* __restrict__ bias_qkv) {
    const int i = blockIdx.x;    // 0..767
    const int c = threadIdx.x;   // 0..255
    const int j = i & 255;
    const int p = ((j & 31) << 3) + (j >> 5);
    const float* Wsrc = (i < 256) ? Wq : (i < 512 ? Wk : Wv);
    const float* bsrc = (i < 256) ? bq : (i < 512 ? bk : bv);
    Wqkv_b[i * 256 + c] = f2bf(Wsrc[p * 256 + c]);
    if (i < 256) Wo_b[i * 256 + c] = f2bf(Wo[i * 256 + c]);
    if (c == 0) bias_qkv[i] = bsrc[p];
}

// --- K1: fused add + QKV GEMM + per-token 8x8 attention --------------------
// block = 512 threads (8 waves), tile T = 64 tokens. LDS = 133 KB.
__launch_bounds__(512, 2)
__global__ void qkv_attn_kernel(const float* __restrict__ x_c, const float* __restrict__ x_t,
                                const u16* __restrict__ Wqkv_b,
                                const float* __restrict__ bias_qkv,
                                u16* __restrict__ O_glob) {
    __shared__ u16 XT[64 * LDX];     // X^T tile [t][c], bf16
    __shared__ u16 QKVT[64 * LQ];    // [t][q 0..255 | k 256..511 | v 512..767]

    const int tid = threadIdx.x;
    const int lane = tid & 63;
    const int wave = tid >> 6;
    const long tok0 = (long)blockIdx.x * 64;
    const int b = (int)(tok0 >> 14);
    const int hw0 = (int)(tok0 & (HWN - 1));
    const float* __restrict__ xc = x_c + (size_t)b * CH * HWN + hw0;
    const float* __restrict__ xt = x_t + (size_t)b * CH * HWN + hw0;

    // Phase 0: stage X^T (fused add + bf16 cast). lane->(t=tid&15, chan pair=tid>>4)
    // LDS write banks: quad = 4*(t%8) + c/2 -> all 32 quads, 2-way -> free.
    {
        const int ltk = tid & 15;
        const int cp = tid >> 4;     // 0..31
        for (int pass = 0; pass < 4; ++pass) {
            const int c0 = pass * 64 + cp * 2;
#pragma unroll
            for (int ts = 0; ts < 4; ++ts) {
                const int t = ts * 16 + ltk;
                const float a0 = xc[c0 * HWN + t] + xt[c0 * HWN + t];
                const float a1 = xc[(c0 + 1) * HWN + t] + xt[(c0 + 1) * HWN + t];
                const unsigned pk = (unsigned)f2bf(a0) | ((unsigned)f2bf(a1) << 16);
                *(unsigned*)&XT[t * LDX + c0] = pk;
            }
        }
    }
    __syncthreads();

    // Phase 1: QKV' = Wqkv' @ X   (M=768, N=64, K=256), 16x16x32 bf16 MFMA.
    // wave w owns rows [w*96, w*96+96), all 4 col-tiles.
    {
        const int l15 = lane & 15;
        const int l4 = lane >> 4;
        const int m_base = wave * 96;
        f32x4 acc[6][4];
#pragma unroll
        for (int i = 0; i < 6; ++i)
#pragma unroll
            for (int j = 0; j < 4; ++j) acc[i][j] = (f32x4){0.f, 0.f, 0.f, 0.f};

#pragma unroll
        for (int kk = 0; kk < 8; ++kk) {
            const int koff = kk * 32 + l4 * 8;
            bf16x8 bfr[4];
#pragma unroll
            for (int ct = 0; ct < 4; ++ct)
                bfr[ct] = __builtin_bit_cast(bf16x8,
                    *(const u16x8*)&XT[(ct * 16 + l15) * LDX + koff]);
#pragma unroll
            for (int mt = 0; mt < 6; ++mt) {
                const int arow = m_base + mt * 16 + l15;
                const bf16x8 afr = __builtin_bit_cast(bf16x8,
                    *(const u16x8*)&Wqkv_b[arow * 256 + koff]);
#pragma unroll
                for (int ct = 0; ct < 4; ++ct)
                    acc[mt][ct] = __builtin_amdgcn_mfma_f32_16x16x32_bf16(
                        afr, bfr[ct], acc[mt][ct], 0, 0, 0);
            }
        }
        // epilogue: +bias, pack 4 consecutive channels -> one b64 LDS write
        #pragma unroll
        for (int mt = 0; mt < 6; ++mt) {
            const int i0 = m_base + mt * 16 + l4 * 4;
            const f32x4 bias = *(const f32x4*)&bias_qkv[i0];
#pragma unroll
            for (int ct = 0; ct < 4; ++ct) {
                const int t = ct * 16 + l15;
                u16x4 pk;
#pragma unroll
                for (int r = 0; r < 4; ++r) pk[r] = f2bf(acc[mt][ct][r] + bias[r]);
                *(u16x4*)&QKVT[t * LQ + i0] = pk;
            }
        }
    }
    __syncthreads();

    // Phase 2: per-token 8x8 cross-head attention. 8 threads/token (one head each).
    // k/v reads are identical across a token's 8 threads -> LDS broadcast,
    // token stride gives distinct bank quads -> conflict-free.
    {
        const int t = tid >> 3;     // 0..63
        const int h = tid & 7;      // head
        const u16* __restrict__ row = &QKVT[t * LQ];
        float q[32];
#pragma unroll
        for (int i = 0; i < 4; ++i) {
            const u16x8 v = *(const u16x8*)&row[h * 32 + i * 8];
#pragma unroll
            for (int e = 0; e < 8; ++e) q[i * 8 + e] = bf2f(v[e]);
        }
        float dot[8];
#pragma unroll
        for (int g = 0; g < 8; ++g) {
            float s = 0.f;
#pragma unroll
            for (int i = 0; i < 4; ++i) {
                const u16x8 v = *(const u16x8*)&row[256 + g * 32 + i * 8];
#pragma unroll
                for (int e = 0; e < 8; ++e) s += q[i * 8 + e] * bf2f(v[e]);
            }
            dot[g] = s * 0.17677669529663687f;   // 32^-0.5
        }
        float m = dot[0];
#pragma unroll
        for (int g = 1; g < 8; ++g) m = fmaxf(m, dot[g]);
        float ssum = 0.f;
#pragma unroll
        for (int g = 0; g < 8; ++g) { dot[g] = __expf(dot[g] - m); ssum += dot[g]; }
        const float rinv = 1.f / ssum;
        float o[32];
#pragma unroll
        for (int i = 0; i < 32; ++i) o[i] = 0.f;
#pragma unroll
        for (int g = 0; g < 8; ++g) {
            const float w = dot[g] * rinv;
#pragma unroll
            for (int i = 0; i < 4; ++i) {
                const u16x8 v = *(const u16x8*)&row[512 + g * 32 + i * 8];
#pragma unroll
                for (int e = 0; e < 8; ++e) o[i * 8 + e] += w * bf2f(v[e]);
            }
        }
        // head-OUTER concat is exactly our channel layout -> contiguous store
        u16* __restrict__ orow = O_glob + (size_t)(tok0 + t) * 256 + h * 32;
#pragma unroll
        for (int i = 0; i < 4; ++i) {
            u16x8 pk;
#pragma unroll
            for (int e = 0; e < 8; ++e) pk[e] = f2bf(o[i * 8 + e]);
            *(u16x8*)&orow[i * 8] = pk;
        }
    }
}

// --- K2: OUT[c][t] = Wo @ O^T + bo, fp32 out in [B][C][H][W] ---------------
__launch_bounds__(256, 2)
__global__ void out_gemm_kernel(const u16* __restrict__ O_glob,
                                const u16* __restrict__ Wo_b,
                                const float* __restrict__ bo,
                                float* __restrict__ out) {
    __shared__ u16 OT[64 * LDX];
    const int tid = threadIdx.x;
    const int lane = tid & 63;
    const int wave = tid >> 6;   // 0..3
    const long tok0 = (long)blockIdx.x * 64;

    // stage O tile (rows are 512B contiguous -> fully coalesced)
#pragma unroll
    for (int i = 0; i < 8; ++i) {
        const int idx = tid + i * 256;      // 0..2047
        const int r = idx >> 5, c8 = idx & 31;
        *(u16x8*)&OT[r * LDX + c8 * 8] =
            *(const u16x8*)&O_glob[(size_t)(tok0 + r) * 256 + c8 * 8];
    }
    __syncthreads();

    const int l15 = lane & 15;
    const int l4 = lane >> 4;
    const int m_base = wave * 64;
    f32x4 acc[4][4];
#pragma unroll
    for (int i = 0; i < 4; ++i)
#pragma unroll
        for (int j = 0; j < 4; ++j) acc[i][j] = (f32x4){0.f, 0.f, 0.f, 0.f};

#pragma unroll
    for (int kk = 0; kk < 8; ++kk) {
        const int koff = kk * 32 + l4 * 8;
        bf16x8 bfr[4];
#pragma unroll
        for (int ct = 0; ct < 4; ++ct)
            bfr[ct] = __builtin_bit_cast(bf16x8,
                *(const u16x8*)&OT[(ct * 16 + l15) * LDX + koff]);
#pragma unroll
        for (int mt = 0; mt < 4; ++mt) {
            const int arow = m_base + mt * 16 + l15;
            const bf16x8 afr = __builtin_bit_cast(bf16x8,
                *(const u16x8*)&Wo_b[arow * 256 + koff]);
#pragma unroll
            for (int ct = 0; ct < 4; ++ct)
                acc[mt][ct] = __builtin_amdgcn_mfma_f32_16x16x32_bf16(
                    afr, bfr[ct], acc[mt][ct], 0, 0, 0);
        }
    }

#pragma unroll
    for (int mt = 0; mt < 4; ++mt) {
        const int c0 = m_base + mt * 16 + l4 * 4;
        const f32x4 bias = *(const f32x4*)&bo[c0];
#pragma unroll
        for (int ct = 0; ct < 4; ++ct) {
            const long t = tok0 + ct * 16 + l15;
            const int bb = (int)(t >> 14);
            const int hw = (int)(t & (HWN - 1));
            float* __restrict__ op = out + (((size_t)bb * 256 + c0) << 14) + hw;
#pragma unroll
            for (int r = 0; r < 4; ++r)
                op[(size_t)r << 14] = acc[mt][ct][r] + bias[r];
        }
    }
}

extern "C" void kernel_launch(void* const* d_in, const int* in_sizes, int n_in,
                              void* d_out, int out_size, void* d_ws, size_t ws_size,
                              hipStream_t stream) {
    const float* x_c = (const float*)d_in[0];
    const float* x_t = (const float*)d_in[1];
    const float* Wq = (const float*)d_in[2];
    const float* bq = (const float*)d_in[3];
    const float* Wk = (const float*)d_in[4];
    const float* bk = (const float*)d_in[5];
    const float* Wv = (const float*)d_in[6];
    const float* bv = (const float*)d_in[7];
    const float* Wo = (const float*)d_in[8];
    const float* bo = (const float*)d_in[9];
    float* out = (float*)d_out;
    char* ws = (char*)d_ws;

    u16* Wqkv_b = (u16*)(ws + WS_WQKV);
    u16* Wo_b = (u16*)(ws + WS_WO);
    float* bias_qkv = (float*)(ws + WS_BIAS);
    u16* O_glob = (u16*)(ws + WS_O);

    prep_kernel<<<768, 256, 0, stream>>>(Wq, Wk, Wv, Wo, bq, bk, bv,
                                         Wqkv_b, Wo_b, bias_qkv);
    qkv_attn_kernel<<<2048, 512, 0, stream>>>(x_c, x_t, Wqkv_b, bias_qkv, O_glob);
    out_gemm_kernel<<<2048, 256, 0, stream>>>(O_glob, Wo_b, bo, out);
}